// Round 1
// baseline (760.086 us; speedup 1.0000x reference)
//
#include <hip/hip_runtime.h>

// ---------------------------------------------------------------------------
// Sigmoid attention, MI355X. B=2 N=2048 C=1024 H=16 dh=64.
// Outputs (f32, concat): attn_matrix [2,16,2048,2048], atv [2,2048,1024],
//                        proj [2,2048,1024].
// Strategy: bf16 MFMA 16x16x32 everywhere (threshold is ~8% relative).
// ---------------------------------------------------------------------------

typedef short short8 __attribute__((ext_vector_type(8)));    // 8 bf16 raw bits
typedef unsigned short ushort8v __attribute__((ext_vector_type(8)));
typedef float f32x4 __attribute__((ext_vector_type(4)));

#define DEV static __device__ __forceinline__

DEV unsigned short f2bf(float f) {          // round-to-nearest-even f32->bf16
  unsigned u = __builtin_bit_cast(unsigned, f);
  u += 0x7FFFu + ((u >> 16) & 1u);
  return (unsigned short)(u >> 16);
}

DEV float sigmoid_fast(float z) {           // 1/(1+e^-z) via v_exp/v_rcp
  float e = __builtin_amdgcn_exp2f(z * -1.44269504f);
  return __builtin_amdgcn_rcpf(1.0f + e);
}

// ---------------------------------------------------------------------------
__global__ void cvt_f32_bf16(const float* __restrict__ in,
                             unsigned short* __restrict__ out, int n4) {
  int i = blockIdx.x * blockDim.x + threadIdx.x;
  if (i >= n4) return;
  float4 f = ((const float4*)in)[i];
  ushort4 o;
  o.x = f2bf(f.x); o.y = f2bf(f.y); o.z = f2bf(f.z); o.w = f2bf(f.w);
  ((ushort4*)out)[i] = o;
}

// ---------------------------------------------------------------------------
// C[M,N] = A[M,K] @ B[N,K]^T, bf16 in / f32 acc. 128x128 tile, BK=64,
// 256 threads = 4 waves in 2x2, each wave 64x64 (4x4 MFMA tiles).
// MODE 0: scatter bf16 into q/k/v [B,H,N,64] sections (stride 4194304 elems).
// MODE 1: plain f32 row-major output.
template<int MODE>
__global__ __launch_bounds__(256) void gemm_bf16_nt(
    const unsigned short* __restrict__ A, const unsigned short* __restrict__ B,
    unsigned short* __restrict__ outQKV, float* __restrict__ outF,
    int M, int N, int K) {
  __shared__ __align__(16) unsigned short At[128 * 72];  // +8 pad: 2-way max
  __shared__ __align__(16) unsigned short Bt[128 * 72];
  const int t = threadIdx.x;
  const int row0 = blockIdx.x * 128, col0 = blockIdx.y * 128;
  const int w = t >> 6, lane = t & 63, lm = lane & 15, quad = lane >> 4;
  const int mb = (w >> 1) * 64, nb = (w & 1) * 64;

  f32x4 acc[4][4];
#pragma unroll
  for (int i = 0; i < 4; i++)
#pragma unroll
    for (int j = 0; j < 4; j++) acc[i][j] = (f32x4)0.0f;

  for (int k0 = 0; k0 < K; k0 += 64) {
#pragma unroll
    for (int i = 0; i < 4; i++) {      // 1024 chunks of 8 bf16 per tile
      int c = t + 256 * i;
      int r = c >> 3, cc = c & 7;
      *(int4*)&At[r * 72 + cc * 8] =
          *(const int4*)&A[(size_t)(row0 + r) * K + k0 + cc * 8];
      *(int4*)&Bt[r * 72 + cc * 8] =
          *(const int4*)&B[(size_t)(col0 + r) * K + k0 + cc * 8];
    }
    __syncthreads();
#pragma unroll
    for (int kk = 0; kk < 64; kk += 32) {
      short8 af[4], bf[4];
#pragma unroll
      for (int i = 0; i < 4; i++)
        af[i] = *(const short8*)&At[(mb + 16 * i + lm) * 72 + kk + quad * 8];
#pragma unroll
      for (int j = 0; j < 4; j++)
        bf[j] = *(const short8*)&Bt[(nb + 16 * j + lm) * 72 + kk + quad * 8];
#pragma unroll
      for (int i = 0; i < 4; i++)
#pragma unroll
        for (int j = 0; j < 4; j++)
          acc[i][j] = __builtin_amdgcn_mfma_f32_16x16x32_bf16(
              af[i], bf[j], acc[i][j], 0, 0, 0);
    }
    __syncthreads();
  }

  // epilogue: C/D layout col=lane&15, row=quad*4+reg
#pragma unroll
  for (int i = 0; i < 4; i++) {
#pragma unroll
    for (int j = 0; j < 4; j++) {
#pragma unroll
      for (int r = 0; r < 4; r++) {
        int rM = row0 + mb + 16 * i + quad * 4 + r;
        int cN = col0 + nb + 16 * j + lm;
        float v = acc[i][j][r];
        if (MODE == 0) {
          // channel cN in [0,3072): s*1024 + h*64 + d ; row rM: b*2048 + n
          int s = cN >> 10, hh = (cN >> 6) & 15, d = cN & 63;
          int b = rM >> 11, nl = rM & 2047;
          outQKV[(size_t)s * 4194304 +
                 ((size_t)((b << 4) + hh) * 2048 + nl) * 64 + d] = f2bf(v);
        } else {
          outF[(size_t)rM * N + cN] = v;
        }
      }
    }
  }
}

// ---------------------------------------------------------------------------
// Fused attention: one block per (b,h,q-tile of 128 rows). 4 waves, each owns
// 32 q-rows. Loops 16 k-tiles of 128: QK^T -> sigmoid -> store P(f32, NT) +
// P(bf16) to wave-private LDS rows -> PV accumulate.
__global__ __launch_bounds__(256) void attn_sigmoid(
    const unsigned short* __restrict__ Q, const unsigned short* __restrict__ Kk,
    const unsigned short* __restrict__ V, float* __restrict__ Pout,
    float* __restrict__ atvF, unsigned short* __restrict__ atvB) {
  __shared__ __align__(16) unsigned short Kt[128 * 72];   // K-tile [128][64]+pad
  __shared__ __align__(16) unsigned short Vt[64 * 136];   // V^T  [64][128]+pad
  __shared__ __align__(16) unsigned short Pl[128 * 136];  // P bf16 [128][128]+pad

  const int t = threadIdx.x;
  const int qt = blockIdx.x & 15, bh = blockIdx.x >> 4;
  const int b = bh >> 4, h = bh & 15;
  const int q0 = qt * 128;
  const int w = t >> 6, lane = t & 63, lm = lane & 15, quad = lane >> 4;

  const unsigned short* qh = Q + (size_t)bh * 2048 * 64;
  const unsigned short* kh = Kk + (size_t)bh * 2048 * 64;
  const unsigned short* vh = V + (size_t)bh * 2048 * 64;
  float* pbase = Pout + (size_t)bh * 2048 * 2048;

  // Q fragments live in registers for the whole kernel (A-operand layout)
  short8 qf[2][2];
#pragma unroll
  for (int i = 0; i < 2; i++)
#pragma unroll
    for (int kc = 0; kc < 2; kc++)
      qf[i][kc] = *(const short8*)&qh[(size_t)(q0 + w * 32 + 16 * i + lm) * 64 +
                                      kc * 32 + quad * 8];

  f32x4 oacc[2][4];
#pragma unroll
  for (int i = 0; i < 2; i++)
#pragma unroll
    for (int n = 0; n < 4; n++) oacc[i][n] = (f32x4)0.0f;

  for (int kt = 0; kt < 16; kt++) {
    const int k0 = kt * 128;
    // ---- stage K-tile (row-major, coalesced 16B) ----
#pragma unroll
    for (int i = 0; i < 4; i++) {
      int c = t + 256 * i;
      int r = c >> 3, cc = c & 7;
      *(int4*)&Kt[r * 72 + cc * 8] =
          *(const int4*)&kh[(size_t)(k0 + r) * 64 + cc * 8];
    }
    // ---- stage V-tile transposed: Vt[d][k] (writes hit all 32 banks) ----
    {
      int r = t & 127;
      int cb = t >> 7;
#pragma unroll
      for (int i = 0; i < 4; i++) {
        int cc = cb + 2 * i;  // chunk of 8 d's
        ushort8v vv = *(const ushort8v*)&vh[(size_t)(k0 + r) * 64 + cc * 8];
#pragma unroll
        for (int l = 0; l < 8; l++) Vt[(cc * 8 + l) * 136 + r] = vv[l];
      }
    }
    __syncthreads();

    // ---- S = Q K^T (wave w -> rows 32w..32w+31, all 128 cols) ----
    f32x4 sacc[2][8];
#pragma unroll
    for (int i = 0; i < 2; i++)
#pragma unroll
      for (int j = 0; j < 8; j++) sacc[i][j] = (f32x4)0.0f;
#pragma unroll
    for (int kc = 0; kc < 2; kc++) {
      short8 bk[8];
#pragma unroll
      for (int j = 0; j < 8; j++)
        bk[j] = *(const short8*)&Kt[(16 * j + lm) * 72 + kc * 32 + quad * 8];
#pragma unroll
      for (int i = 0; i < 2; i++)
#pragma unroll
        for (int j = 0; j < 8; j++)
          sacc[i][j] = __builtin_amdgcn_mfma_f32_16x16x32_bf16(
              qf[i][kc], bk[j], sacc[i][j], 0, 0, 0);
    }

    // ---- sigmoid, stream P to global (f32, NT), bf16 P to private LDS ----
#pragma unroll
    for (int i = 0; i < 2; i++) {
#pragma unroll
      for (int j = 0; j < 8; j++) {
#pragma unroll
        for (int r = 0; r < 4; r++) {
          float s = sigmoid_fast(sacc[i][j][r] * 0.125f - 7.625f);
          int rt = w * 32 + 16 * i + quad * 4 + r;
          int ct = 16 * j + lm;
          __builtin_nontemporal_store(
              s, &pbase[(size_t)(q0 + rt) * 2048 + k0 + ct]);
          Pl[rt * 136 + ct] = f2bf(s);
        }
      }
    }
    __syncthreads();

    // ---- O += P V  (A from private Pl rows, B from Vt) ----
#pragma unroll
    for (int kc = 0; kc < 4; kc++) {
      short8 ap[2], bv[4];
#pragma unroll
      for (int i = 0; i < 2; i++)
        ap[i] = *(const short8*)&Pl[(w * 32 + 16 * i + lm) * 136 + kc * 32 +
                                    quad * 8];
#pragma unroll
      for (int n = 0; n < 4; n++)
        bv[n] = *(const short8*)&Vt[(16 * n + lm) * 136 + kc * 32 + quad * 8];
#pragma unroll
      for (int i = 0; i < 2; i++)
#pragma unroll
        for (int n = 0; n < 4; n++)
          oacc[i][n] = __builtin_amdgcn_mfma_f32_16x16x32_bf16(
              ap[i], bv[n], oacc[i][n], 0, 0, 0);
    }
    __syncthreads();
  }

  // ---- epilogue: atv [B,N,H*64] f32 + bf16 copy for proj GEMM ----
#pragma unroll
  for (int i = 0; i < 2; i++) {
#pragma unroll
    for (int n = 0; n < 4; n++) {
#pragma unroll
      for (int r = 0; r < 4; r++) {
        int grow = q0 + w * 32 + 16 * i + quad * 4 + r;
        int gcol = h * 64 + 16 * n + lm;
        size_t idx = ((size_t)(b * 2048 + grow)) * 1024 + gcol;
        float v = oacc[i][n][r];
        atvF[idx] = v;
        atvB[idx] = f2bf(v);
      }
    }
  }
}

// ---------------------------------------------------------------------------
extern "C" void kernel_launch(void* const* d_in, const int* in_sizes, int n_in,
                              void* d_out, int out_size, void* d_ws,
                              size_t ws_size, hipStream_t stream) {
  const float* x = (const float*)d_in[0];        // [2,2048,1024]
  const float* w_qkv = (const float*)d_in[1];    // [3072,1024]
  const float* w_proj = (const float*)d_in[2];   // [1024,1024]

  float* Pout = (float*)d_out;                         // 134217728 floats
  float* atvOut = (float*)d_out + 134217728;           // 4194304 floats
  float* projOut = (float*)d_out + 138412032;          // 4194304 floats

  unsigned char* ws = (unsigned char*)d_ws;
  unsigned short* xbf = (unsigned short*)(ws + 0);             // 8 MB
  unsigned short* wqkvbf = (unsigned short*)(ws + 8388608);    // 6 MB
  unsigned short* wprojbf = (unsigned short*)(ws + 14680064);  // 2 MB
  unsigned short* qb = (unsigned short*)(ws + 16777216);       // 8 MB
  unsigned short* kb = (unsigned short*)(ws + 25165824);       // 8 MB
  unsigned short* vb = (unsigned short*)(ws + 33554432);       // 8 MB
  unsigned short* atvbf = (unsigned short*)(ws + 41943040);    // 8 MB

  cvt_f32_bf16<<<4096, 256, 0, stream>>>(x, xbf, 1048576);
  cvt_f32_bf16<<<3072, 256, 0, stream>>>(w_qkv, wqkvbf, 786432);
  cvt_f32_bf16<<<1024, 256, 0, stream>>>(w_proj, wprojbf, 262144);

  gemm_bf16_nt<0><<<dim3(32, 24), 256, 0, stream>>>(xbf, wqkvbf, qb, nullptr,
                                                    4096, 3072, 1024);

  attn_sigmoid<<<512, 256, 0, stream>>>(qb, kb, vb, Pout, atvOut, atvbf);

  gemm_bf16_nt<1><<<dim3(32, 8), 256, 0, stream>>>(atvbf, wprojbf, nullptr,
                                                   projOut, 4096, 1024, 1024);
}